// Round 1
// baseline (3347.157 us; speedup 1.0000x reference)
//
#include <hip/hip_runtime.h>
#include <math.h>

// ---------------- problem constants ----------------
#define NB     8
#define NT     1000
#define NMEL   80
#define NFREQ  513      // 1024/2+1
#define NFFT   1024
#define WINL   1024
#define HOP    256
#define SIGL   256768   // (NT-1)*HOP + WINL
#define NFRM   8000     // NB*NT
#define NPH    4104000  // NFRM*NFREQ
#define NITER  8

// JAX threefry mode: 1 = partitionable (modern default), 0 = legacy concat-halves
#define TFG_PARTITIONABLE 1

// ---------------- workspace layout (bytes) ----------------
#define OFF_AUG    ((size_t)0)                       // double aug[80][160]
#define SZ_AUG     ((size_t)80*160*8)                // 102400
#define OFF_INVMEL (OFF_AUG + SZ_AUG)                // float invmel[513][80]
#define SZ_INVMEL  ((size_t)NFREQ*NMEL*4)            // 164160
#define OFF_WINF   (OFF_INVMEL + SZ_INVMEL)          // float winf[1024]
#define OFF_WINS   (OFF_WINF + 4096)                 // float wins[1024]
#define OFF_TW     (OFF_WINS + 4096)                 // float2 tw[512]
#define OFF_MAG    (OFF_TW + 4096)                   // float mag[8000][513]
#define SZ_MAG     ((size_t)NFRM*NFREQ*4)
#define OFF_PH     (OFF_MAG + SZ_MAG)                // float2 phase[8000][513]
#define SZ_PH      ((size_t)NFRM*NFREQ*8)
#define OFF_MP     (OFF_PH + SZ_PH)                  // float melpow[8000][80]
#define SZ_MP      ((size_t)NFRM*NMEL*4)
#define OFF_FR     (OFF_MP + SZ_MP)                  // float frames[8000][1024]
#define SZ_FR      ((size_t)NFRM*NFFT*4)
#define OFF_SIG    (OFF_FR + SZ_FR)                  // float sig[8][256768]
#define SZ_SIG     ((size_t)NB*SIGL*4)

// ---------------- small precompute kernels ----------------

__global__ void k_windows(float* __restrict__ winf, float* __restrict__ wins,
                          float2* __restrict__ tw) {
    int t = threadIdx.x; // 256 threads
    for (int n = t; n < WINL; n += 256) {
        double w = 0.5 - 0.5 * cos(2.0 * M_PI * (double)n / (double)WINL);
        winf[n] = (float)w;
    }
    __syncthreads();
    // den[j] = sum_k winf[j+256k]^2 (f32, sequential like numpy), syn = w/den[j%256]
    {
        float a0 = winf[t], a1 = winf[t + 256], a2 = winf[t + 512], a3 = winf[t + 768];
        float den = a0 * a0;
        den += a1 * a1; den += a2 * a2; den += a3 * a3;
        wins[t]       = a0 / den;
        wins[t + 256] = a1 / den;
        wins[t + 512] = a2 / den;
        wins[t + 768] = a3 / den;
    }
    for (int k = t; k < 512; k += 256) {
        double ang = -2.0 * M_PI * (double)k / (double)NFFT;
        tw[k] = make_float2((float)cos(ang), (float)sin(ang));
    }
}

// G = B B^T (f64), build augmented [G | I] in ws
__global__ void k_gram(const float* __restrict__ Bm, double* __restrict__ aug) {
    int i = blockIdx.x; // 80 blocks
    for (int j = threadIdx.x; j < 160; j += blockDim.x) {
        if (j < 80) {
            double s = 0.0;
            for (int f = 0; f < NFREQ; ++f)
                s += (double)Bm[i * NFREQ + f] * (double)Bm[j * NFREQ + f];
            aug[i * 160 + j] = s;
        } else {
            aug[i * 160 + j] = ((j - 80) == i) ? 1.0 : 0.0;
        }
    }
}

// Gauss-Jordan inversion of SPD 80x80 (no pivoting needed), in global ws
__global__ void k_gj(double* __restrict__ aug) {
    __shared__ double pivinv;
    for (int p = 0; p < 80; ++p) {
        if (threadIdx.x == 0) pivinv = 1.0 / aug[p * 160 + p];
        __syncthreads();
        for (int j = threadIdx.x; j < 160; j += blockDim.x) aug[p * 160 + j] *= pivinv;
        __syncthreads();
        int i = threadIdx.x;
        if (i < 80 && i != p) {
            double fct = aug[i * 160 + p];
            for (int j = 0; j < 160; ++j) aug[i * 160 + j] -= fct * aug[p * 160 + j];
        }
        __syncthreads();
    }
}

// invmel[f][m] = sum_k B[k][f] * Ginv[k][m]
__global__ void k_invmel(const float* __restrict__ Bm, const double* __restrict__ aug,
                         float* __restrict__ invmel) {
    int idx = blockIdx.x * blockDim.x + threadIdx.x;
    if (idx >= NFREQ * NMEL) return;
    int f = idx / NMEL, m = idx - f * NMEL;
    double s = 0.0;
    for (int k = 0; k < NMEL; ++k)
        s += (double)Bm[k * NFREQ + f] * aug[k * 160 + 80 + m];
    invmel[idx] = (float)s;
}

// melpow = 10^(mel*scale + mean)
__global__ void k_melpow(const float* __restrict__ mel, const float* __restrict__ smean,
                         const float* __restrict__ sscale, float* __restrict__ mp) {
    int idx = blockIdx.x * blockDim.x + threadIdx.x;
    if (idx >= NFRM * NMEL) return;
    int m = idx % NMEL;
    mp[idx] = exp10f(mel[idx] * sscale[m] + smean[m]);
}

// mag[bt][f] = max(1e-10, sum_m melpow[bt][m]*invmel[f][m])
__global__ __launch_bounds__(256) void k_mag(const float* __restrict__ mp,
                                             const float* __restrict__ invmel,
                                             float* __restrict__ mag) {
    __shared__ float row[NMEL];
    int bt = blockIdx.x;
    for (int m = threadIdx.x; m < NMEL; m += 256) row[m] = mp[(size_t)bt * NMEL + m];
    __syncthreads();
    for (int f = threadIdx.x; f < NFREQ; f += 256) {
        float s = 0.f;
        const float* iv = invmel + (size_t)f * NMEL;
        for (int m = 0; m < NMEL; ++m) s += row[m] * iv[m];
        mag[(size_t)bt * NFREQ + f] = fmaxf(1e-10f, s);
    }
}

// ---------------- threefry2x32 (JAX-exact) ----------------
__device__ inline unsigned rotl32(unsigned x, int d) { return (x << d) | (x >> (32 - d)); }

__device__ inline void threefry2x32(unsigned k0, unsigned k1, unsigned& x0, unsigned& x1) {
    unsigned ks0 = k0, ks1 = k1, ks2 = k0 ^ k1 ^ 0x1BD11BDAu;
    x0 += ks0; x1 += ks1;
#define TFR(r) { x0 += x1; x1 = rotl32(x1, r); x1 ^= x0; }
    TFR(13) TFR(15) TFR(26) TFR(6)   x0 += ks1; x1 += ks2 + 1u;
    TFR(17) TFR(29) TFR(16) TFR(24)  x0 += ks2; x1 += ks0 + 2u;
    TFR(13) TFR(15) TFR(26) TFR(6)   x0 += ks0; x1 += ks1 + 3u;
    TFR(17) TFR(29) TFR(16) TFR(24)  x0 += ks1; x1 += ks2 + 4u;
    TFR(13) TFR(15) TFR(26) TFR(6)   x0 += ks2; x1 += ks0 + 5u;
#undef TFR
}

__device__ inline float bits_to_unit(unsigned bits) {
    return __uint_as_float((bits >> 9) | 0x3F800000u) - 1.0f;
}

__device__ inline float2 unit_to_phase(float u) {
    float ang = 6.283185307179586f * u; // f32(2*pi)
    return make_float2(cosf(ang), sinf(ang));
}

__global__ void k_phase_init(float2* __restrict__ phase) {
#if TFG_PARTITIONABLE
    int i = blockIdx.x * blockDim.x + threadIdx.x;
    if (i >= NPH) return;
    unsigned x0 = 0u, x1 = (unsigned)i; // 64-bit counter = flat index (hi=0, lo=i)
    threefry2x32(0u, 1u, x0, x1);       // key(1) -> (0,1)
    unsigned bits = x0 ^ x1;
    phase[i] = unit_to_phase(bits_to_unit(bits));
#else
    const int half = NPH / 2;
    int i = blockIdx.x * blockDim.x + threadIdx.x;
    if (i >= half) return;
    unsigned x0 = (unsigned)i, x1 = (unsigned)(i + half);
    threefry2x32(0u, 1u, x0, x1);
    phase[i]        = unit_to_phase(bits_to_unit(x0));
    phase[i + half] = unit_to_phase(bits_to_unit(x1));
#endif
}

// ---------------- 1024-pt Stockham FFT in LDS ----------------
// Result ends in `a` (even number of stages), natural order.
template <bool INV>
__device__ inline void fft1024_dev(float2* a, float2* b, const float2* __restrict__ tw) {
    int n = NFFT;
    int s_log = 0;
    int tsh = 0;
#pragma unroll
    for (int stage = 0; stage < 10; ++stage) {
        int m = n >> 1;
        int s = 1 << s_log;
        for (int w = threadIdx.x; w < 512; w += 256) {
            int q = w & (s - 1);
            int p = w >> s_log;
            float2 x0 = a[q + s * p];
            float2 x1 = a[q + s * (p + m)];
            float2 su = make_float2(x0.x + x1.x, x0.y + x1.y);
            float2 di = make_float2(x0.x - x1.x, x0.y - x1.y);
            float2 wp = tw[p << tsh];
            float wy = INV ? -wp.y : wp.y;
            float2 pr = make_float2(di.x * wp.x - di.y * wy, di.x * wy + di.y * wp.x);
            b[q + s * (2 * p)]     = su;
            b[q + s * (2 * p + 1)] = pr;
        }
        __syncthreads();
        float2* t2 = a; a = b; b = t2;
        n = m; s_log += 1; tsh += 1;
    }
}

// ISTFT frame: spec = mag*phase -> Hermitian extend -> ifft -> *syn_win -> frames
__global__ __launch_bounds__(256) void k_istft(const float* __restrict__ mag,
                                               const float2* __restrict__ phase,
                                               const float* __restrict__ wins,
                                               const float2* __restrict__ twg,
                                               float* __restrict__ frames) {
    __shared__ float2 bufA[NFFT];
    __shared__ float2 bufB[NFFT];
    __shared__ float2 tws[512];
    int bt = blockIdx.x;
    const float*  mg = mag   + (size_t)bt * NFREQ;
    const float2* ph = phase + (size_t)bt * NFREQ;
    for (int k = threadIdx.x; k < 512; k += 256) tws[k] = twg[k];
    for (int k = threadIdx.x; k < NFFT; k += 256) {
        float2 s;
        if (k <= 512) {
            float m = mg[k]; float2 p = ph[k];
            s = make_float2(m * p.x, m * p.y);
        } else {
            int kk = NFFT - k;
            float m = mg[kk]; float2 p = ph[kk];
            s = make_float2(m * p.x, -m * p.y);
        }
        bufA[k] = s;
    }
    __syncthreads();
    fft1024_dev<true>(bufA, bufB, tws);
    float* out = frames + (size_t)bt * NFFT;
    const float inv = 1.0f / (float)NFFT;
    for (int n = threadIdx.x; n < NFFT; n += 256)
        out[n] = bufA[n].x * inv * wins[n];
}

// overlap-add (gather): sig[b][l] = sum_t frames[b*NT+t][l-256t]
__global__ void k_ola(const float* __restrict__ frames, float* __restrict__ sig) {
    int idx = blockIdx.x * blockDim.x + threadIdx.x;
    if (idx >= NB * SIGL) return;
    int b = idx / SIGL, l = idx - b * SIGL;
    int tmax = min(NT - 1, l >> 8);
    int tmin = (l >= WINL) ? ((l - (WINL - HOP)) >> 8) : 0; // ceil((l-1023)/256)
    float s = 0.f;
    for (int t = tmin; t <= tmax; ++t)
        s += frames[((size_t)(b * NT + t)) * NFFT + (l - (t << 8))];
    sig[idx] = s;
}

// STFT frame + phase normalize: p = fft(sig_frame*win); phase = p/max(1e-10,|p|)
__global__ __launch_bounds__(256) void k_stft(const float* __restrict__ sig,
                                              const float* __restrict__ winf,
                                              const float2* __restrict__ twg,
                                              float2* __restrict__ phase) {
    __shared__ float2 bufA[NFFT];
    __shared__ float2 bufB[NFFT];
    __shared__ float2 tws[512];
    int bt = blockIdx.x;
    int b = bt / NT, tt = bt - b * NT;
    const float* x = sig + (size_t)b * SIGL + (size_t)tt * HOP;
    for (int k = threadIdx.x; k < 512; k += 256) tws[k] = twg[k];
    for (int n = threadIdx.x; n < NFFT; n += 256)
        bufA[n] = make_float2(x[n] * winf[n], 0.f);
    __syncthreads();
    fft1024_dev<false>(bufA, bufB, tws);
    for (int f = threadIdx.x; f <= 512; f += 256) {
        float2 p = bufA[f];
        float a = sqrtf(p.x * p.x + p.y * p.y);
        float inv = 1.0f / fmaxf(1e-10f, a);
        phase[(size_t)bt * NFREQ + f] = make_float2(p.x * inv, p.y * inv);
    }
}

// ---------------- launcher ----------------
extern "C" void kernel_launch(void* const* d_in, const int* in_sizes, int n_in,
                              void* d_out, int out_size, void* d_ws, size_t ws_size,
                              hipStream_t stream) {
    const float* mel    = (const float*)d_in[0];
    const float* basis  = (const float*)d_in[1];
    const float* smean  = (const float*)d_in[2];
    const float* sscale = (const float*)d_in[3];
    // d_in[4] = n_iter (device scalar); graph capture requires a fixed sequence -> NITER=8.

    char* ws = (char*)d_ws;
    double* aug    = (double*)(ws + OFF_AUG);
    float*  invmel = (float*) (ws + OFF_INVMEL);
    float*  winf   = (float*) (ws + OFF_WINF);
    float*  wins   = (float*) (ws + OFF_WINS);
    float2* tw     = (float2*)(ws + OFF_TW);
    float*  mag    = (float*) (ws + OFF_MAG);
    float2* phase  = (float2*)(ws + OFF_PH);
    float*  mp     = (float*) (ws + OFF_MP);
    float*  frames = (float*) (ws + OFF_FR);
    float*  sig    = (float*) (ws + OFF_SIG);
    float*  outp   = (float*)d_out;

    k_windows<<<1, 256, 0, stream>>>(winf, wins, tw);
    k_gram<<<80, 256, 0, stream>>>(basis, aug);
    k_gj<<<1, 256, 0, stream>>>(aug);
    k_invmel<<<(NFREQ * NMEL + 255) / 256, 256, 0, stream>>>(basis, aug, invmel);
    k_melpow<<<(NFRM * NMEL + 255) / 256, 256, 0, stream>>>(mel, smean, sscale, mp);
    k_mag<<<NFRM, 256, 0, stream>>>(mp, invmel, mag);
#if TFG_PARTITIONABLE
    k_phase_init<<<(NPH + 255) / 256, 256, 0, stream>>>(phase);
#else
    k_phase_init<<<(NPH / 2 + 255) / 256, 256, 0, stream>>>(phase);
#endif

    for (int it = 0; it < NITER; ++it) {
        k_istft<<<NFRM, 256, 0, stream>>>(mag, phase, wins, tw, frames);
        k_ola<<<(NB * SIGL + 255) / 256, 256, 0, stream>>>(frames, sig);
        k_stft<<<NFRM, 256, 0, stream>>>(sig, winf, tw, phase);
    }
    // final ISTFT -> d_out
    k_istft<<<NFRM, 256, 0, stream>>>(mag, phase, wins, tw, frames);
    k_ola<<<(NB * SIGL + 255) / 256, 256, 0, stream>>>(frames, outp);
}

// Round 2
// 1250.879 us; speedup vs baseline: 2.6758x; 2.6758x over previous
//
#include <hip/hip_runtime.h>
#include <math.h>

// ---------------- problem constants ----------------
#define NB     8
#define NT     1000
#define NMEL   80
#define NFREQ  513      // 1024/2+1
#define NFFT   1024
#define WINL   1024
#define HOP    256
#define SIGL   256768   // (NT-1)*HOP + WINL
#define NFRM   8000     // NB*NT
#define NPH    4104000  // NFRM*NFREQ
#define NITER  8

#define TFG_PARTITIONABLE 1

// ---------------- workspace layout (bytes) ----------------
#define OFF_G      ((size_t)0)                       // double G[80][80]
#define SZ_G       ((size_t)NMEL*NMEL*8)             // 51200
#define OFF_GINV   (OFF_G + SZ_G)                    // double Ginv[80][80]
#define SZ_GINV    ((size_t)NMEL*NMEL*8)             // 51200
#define OFF_INVMEL (OFF_GINV + SZ_GINV)              // float invmel[513][80]
#define SZ_INVMEL  ((size_t)NFREQ*NMEL*4)
#define OFF_WINF   (OFF_INVMEL + SZ_INVMEL)          // float winf[1024]
#define OFF_WINS   (OFF_WINF + 4096)                 // float wins[1024]
#define OFF_TW     (OFF_WINS + 4096)                 // float2 tw[512]
#define OFF_MAG    (OFF_TW + 4096)                   // float mag[8000][513]
#define SZ_MAG     ((size_t)NFRM*NFREQ*4)
#define OFF_PH     (OFF_MAG + SZ_MAG)                // float2 phase[8000][513]
#define SZ_PH      ((size_t)NFRM*NFREQ*8)
#define OFF_MP     (OFF_PH + SZ_PH)                  // float melpow[8000][80]
#define SZ_MP      ((size_t)NFRM*NMEL*4)
#define OFF_FR     (OFF_MP + SZ_MP)                  // float frames[8000][1024]
#define SZ_FR      ((size_t)NFRM*NFFT*4)
#define OFF_SIG    (OFF_FR + SZ_FR)                  // float sig[8][256768]
#define SZ_SIG     ((size_t)NB*SIGL*4)

// ---------------- small precompute kernels ----------------

__global__ void k_windows(float* __restrict__ winf, float* __restrict__ wins,
                          float2* __restrict__ tw) {
    int t = threadIdx.x; // 256 threads
    for (int n = t; n < WINL; n += 256) {
        double w = 0.5 - 0.5 * cos(2.0 * M_PI * (double)n / (double)WINL);
        winf[n] = (float)w;
    }
    __syncthreads();
    {
        float a0 = winf[t], a1 = winf[t + 256], a2 = winf[t + 512], a3 = winf[t + 768];
        float den = a0 * a0;
        den += a1 * a1; den += a2 * a2; den += a3 * a3;
        wins[t]       = a0 / den;
        wins[t + 256] = a1 / den;
        wins[t + 512] = a2 / den;
        wins[t + 768] = a3 / den;
    }
    for (int k = t; k < 512; k += 256) {
        double ang = -2.0 * M_PI * (double)k / (double)NFFT;
        tw[k] = make_float2((float)cos(ang), (float)sin(ang));
    }
}

// G = B B^T (f64)
__global__ void k_gram(const float* __restrict__ Bm, double* __restrict__ G) {
    int i = blockIdx.x; // 80 blocks
    for (int j = threadIdx.x; j < NMEL; j += blockDim.x) {
        double s = 0.0;
        for (int f = 0; f < NFREQ; ++f)
            s += (double)Bm[i * NFREQ + f] * (double)Bm[j * NFREQ + f];
        G[i * NMEL + j] = s;
    }
}

// In-place Gauss-Jordan inversion of SPD 80x80, fully in LDS.
// Implicit-identity form: after all pivots, A holds A^{-1}.
__global__ __launch_bounds__(256) void k_gjinv(const double* __restrict__ G,
                                               double* __restrict__ Ginv) {
    __shared__ double A[NMEL][NMEL + 1];
    __shared__ double fcol[NMEL];
    __shared__ double d;
    int t = threadIdx.x;
    for (int e = t; e < NMEL * NMEL; e += 256) A[e / NMEL][e % NMEL] = G[e];
    __syncthreads();
    for (int p = 0; p < NMEL; ++p) {
        if (t < NMEL) fcol[t] = A[t][p];
        if (t == 0) d = 1.0 / A[p][p];
        __syncthreads();
        for (int j = t; j < NMEL; j += 256) A[p][j] = (j == p) ? d : A[p][j] * d;
        __syncthreads();
        for (int e = t; e < NMEL * NMEL; e += 256) {
            int i = e / NMEL, j = e - i * NMEL;
            if (i != p)
                A[i][j] = (j == p) ? (-fcol[i] * d) : (A[i][j] - fcol[i] * A[p][j]);
        }
        __syncthreads();
    }
    for (int e = t; e < NMEL * NMEL; e += 256) Ginv[e] = A[e / NMEL][e % NMEL];
}

// invmel[f][m] = sum_k B[k][f] * Ginv[k][m]
__global__ void k_invmel(const float* __restrict__ Bm, const double* __restrict__ Ginv,
                         float* __restrict__ invmel) {
    int idx = blockIdx.x * blockDim.x + threadIdx.x;
    if (idx >= NFREQ * NMEL) return;
    int f = idx / NMEL, m = idx - f * NMEL;
    double s = 0.0;
    for (int k = 0; k < NMEL; ++k)
        s += (double)Bm[k * NFREQ + f] * Ginv[k * NMEL + m];
    invmel[idx] = (float)s;
}

// melpow = 10^(mel*scale + mean)
__global__ void k_melpow(const float* __restrict__ mel, const float* __restrict__ smean,
                         const float* __restrict__ sscale, float* __restrict__ mp) {
    int idx = blockIdx.x * blockDim.x + threadIdx.x;
    if (idx >= NFRM * NMEL) return;
    int m = idx % NMEL;
    mp[idx] = exp10f(mel[idx] * sscale[m] + smean[m]);
}

// mag[bt][f] = max(1e-10, sum_m melpow[bt][m]*invmel[f][m])
__global__ __launch_bounds__(256) void k_mag(const float* __restrict__ mp,
                                             const float* __restrict__ invmel,
                                             float* __restrict__ mag) {
    __shared__ float row[NMEL];
    int bt = blockIdx.x;
    for (int m = threadIdx.x; m < NMEL; m += 256) row[m] = mp[(size_t)bt * NMEL + m];
    __syncthreads();
    for (int f = threadIdx.x; f < NFREQ; f += 256) {
        float s = 0.f;
        const float* iv = invmel + (size_t)f * NMEL;
        for (int m = 0; m < NMEL; ++m) s += row[m] * iv[m];
        mag[(size_t)bt * NFREQ + f] = fmaxf(1e-10f, s);
    }
}

// ---------------- threefry2x32 (JAX-exact) ----------------
__device__ inline unsigned rotl32(unsigned x, int d) { return (x << d) | (x >> (32 - d)); }

__device__ inline void threefry2x32(unsigned k0, unsigned k1, unsigned& x0, unsigned& x1) {
    unsigned ks0 = k0, ks1 = k1, ks2 = k0 ^ k1 ^ 0x1BD11BDAu;
    x0 += ks0; x1 += ks1;
#define TFR(r) { x0 += x1; x1 = rotl32(x1, r); x1 ^= x0; }
    TFR(13) TFR(15) TFR(26) TFR(6)   x0 += ks1; x1 += ks2 + 1u;
    TFR(17) TFR(29) TFR(16) TFR(24)  x0 += ks2; x1 += ks0 + 2u;
    TFR(13) TFR(15) TFR(26) TFR(6)   x0 += ks0; x1 += ks1 + 3u;
    TFR(17) TFR(29) TFR(16) TFR(24)  x0 += ks1; x1 += ks2 + 4u;
    TFR(13) TFR(15) TFR(26) TFR(6)   x0 += ks2; x1 += ks0 + 5u;
#undef TFR
}

__device__ inline float bits_to_unit(unsigned bits) {
    return __uint_as_float((bits >> 9) | 0x3F800000u) - 1.0f;
}

__device__ inline float2 unit_to_phase(float u) {
    float ang = 6.283185307179586f * u;
    return make_float2(cosf(ang), sinf(ang));
}

__global__ void k_phase_init(float2* __restrict__ phase) {
#if TFG_PARTITIONABLE
    int i = blockIdx.x * blockDim.x + threadIdx.x;
    if (i >= NPH) return;
    unsigned x0 = 0u, x1 = (unsigned)i;
    threefry2x32(0u, 1u, x0, x1);
    unsigned bits = x0 ^ x1;
    phase[i] = unit_to_phase(bits_to_unit(bits));
#else
    const int half = NPH / 2;
    int i = blockIdx.x * blockDim.x + threadIdx.x;
    if (i >= half) return;
    unsigned x0 = (unsigned)i, x1 = (unsigned)(i + half);
    threefry2x32(0u, 1u, x0, x1);
    phase[i]        = unit_to_phase(bits_to_unit(x0));
    phase[i + half] = unit_to_phase(bits_to_unit(x1));
#endif
}

// ---------------- 1024-pt Stockham FFT in LDS ----------------
template <bool INV>
__device__ inline void fft1024_dev(float2* a, float2* b, const float2* __restrict__ tw) {
    int n = NFFT;
    int s_log = 0;
    int tsh = 0;
#pragma unroll
    for (int stage = 0; stage < 10; ++stage) {
        int m = n >> 1;
        int s = 1 << s_log;
        for (int w = threadIdx.x; w < 512; w += 256) {
            int q = w & (s - 1);
            int p = w >> s_log;
            float2 x0 = a[q + s * p];
            float2 x1 = a[q + s * (p + m)];
            float2 su = make_float2(x0.x + x1.x, x0.y + x1.y);
            float2 di = make_float2(x0.x - x1.x, x0.y - x1.y);
            float2 wp = tw[p << tsh];
            float wy = INV ? -wp.y : wp.y;
            float2 pr = make_float2(di.x * wp.x - di.y * wy, di.x * wy + di.y * wp.x);
            b[q + s * (2 * p)]     = su;
            b[q + s * (2 * p + 1)] = pr;
        }
        __syncthreads();
        float2* t2 = a; a = b; b = t2;
        n = m; s_log += 1; tsh += 1;
    }
}

// ISTFT frame: spec = mag*phase -> Hermitian extend -> ifft -> *syn_win -> frames
__global__ __launch_bounds__(256) void k_istft(const float* __restrict__ mag,
                                               const float2* __restrict__ phase,
                                               const float* __restrict__ wins,
                                               const float2* __restrict__ twg,
                                               float* __restrict__ frames) {
    __shared__ float2 bufA[NFFT];
    __shared__ float2 bufB[NFFT];
    __shared__ float2 tws[512];
    int bt = blockIdx.x;
    const float*  mg = mag   + (size_t)bt * NFREQ;
    const float2* ph = phase + (size_t)bt * NFREQ;
    for (int k = threadIdx.x; k < 512; k += 256) tws[k] = twg[k];
    for (int k = threadIdx.x; k < NFFT; k += 256) {
        float2 s;
        if (k <= 512) {
            float m = mg[k]; float2 p = ph[k];
            s = make_float2(m * p.x, m * p.y);
        } else {
            int kk = NFFT - k;
            float m = mg[kk]; float2 p = ph[kk];
            s = make_float2(m * p.x, -m * p.y);
        }
        bufA[k] = s;
    }
    __syncthreads();
    fft1024_dev<true>(bufA, bufB, tws);
    float* out = frames + (size_t)bt * NFFT;
    const float inv = 1.0f / (float)NFFT;
    for (int n = threadIdx.x; n < NFFT; n += 256)
        out[n] = bufA[n].x * inv * wins[n];
}

// overlap-add (gather): sig[b][l] = sum_t frames[b*NT+t][l-256t]
__global__ void k_ola(const float* __restrict__ frames, float* __restrict__ sig) {
    int idx = blockIdx.x * blockDim.x + threadIdx.x;
    if (idx >= NB * SIGL) return;
    int b = idx / SIGL, l = idx - b * SIGL;
    int tmax = min(NT - 1, l >> 8);
    int tmin = (l >= WINL) ? ((l - (WINL - HOP)) >> 8) : 0;
    float s = 0.f;
    for (int t = tmin; t <= tmax; ++t)
        s += frames[((size_t)(b * NT + t)) * NFFT + (l - (t << 8))];
    sig[idx] = s;
}

// STFT frame + phase normalize
__global__ __launch_bounds__(256) void k_stft(const float* __restrict__ sig,
                                              const float* __restrict__ winf,
                                              const float2* __restrict__ twg,
                                              float2* __restrict__ phase) {
    __shared__ float2 bufA[NFFT];
    __shared__ float2 bufB[NFFT];
    __shared__ float2 tws[512];
    int bt = blockIdx.x;
    int b = bt / NT, tt = bt - b * NT;
    const float* x = sig + (size_t)b * SIGL + (size_t)tt * HOP;
    for (int k = threadIdx.x; k < 512; k += 256) tws[k] = twg[k];
    for (int n = threadIdx.x; n < NFFT; n += 256)
        bufA[n] = make_float2(x[n] * winf[n], 0.f);
    __syncthreads();
    fft1024_dev<false>(bufA, bufB, tws);
    for (int f = threadIdx.x; f <= 512; f += 256) {
        float2 p = bufA[f];
        float a = sqrtf(p.x * p.x + p.y * p.y);
        float inv = 1.0f / fmaxf(1e-10f, a);
        phase[(size_t)bt * NFREQ + f] = make_float2(p.x * inv, p.y * inv);
    }
}

// ---------------- launcher ----------------
extern "C" void kernel_launch(void* const* d_in, const int* in_sizes, int n_in,
                              void* d_out, int out_size, void* d_ws, size_t ws_size,
                              hipStream_t stream) {
    const float* mel    = (const float*)d_in[0];
    const float* basis  = (const float*)d_in[1];
    const float* smean  = (const float*)d_in[2];
    const float* sscale = (const float*)d_in[3];

    char* ws = (char*)d_ws;
    double* G      = (double*)(ws + OFF_G);
    double* Ginv   = (double*)(ws + OFF_GINV);
    float*  invmel = (float*) (ws + OFF_INVMEL);
    float*  winf   = (float*) (ws + OFF_WINF);
    float*  wins   = (float*) (ws + OFF_WINS);
    float2* tw     = (float2*)(ws + OFF_TW);
    float*  mag    = (float*) (ws + OFF_MAG);
    float2* phase  = (float2*)(ws + OFF_PH);
    float*  mp     = (float*) (ws + OFF_MP);
    float*  frames = (float*) (ws + OFF_FR);
    float*  sig    = (float*) (ws + OFF_SIG);
    float*  outp   = (float*)d_out;

    k_windows<<<1, 256, 0, stream>>>(winf, wins, tw);
    k_gram<<<80, 256, 0, stream>>>(basis, G);
    k_gjinv<<<1, 256, 0, stream>>>(G, Ginv);
    k_invmel<<<(NFREQ * NMEL + 255) / 256, 256, 0, stream>>>(basis, Ginv, invmel);
    k_melpow<<<(NFRM * NMEL + 255) / 256, 256, 0, stream>>>(mel, smean, sscale, mp);
    k_mag<<<NFRM, 256, 0, stream>>>(mp, invmel, mag);
#if TFG_PARTITIONABLE
    k_phase_init<<<(NPH + 255) / 256, 256, 0, stream>>>(phase);
#else
    k_phase_init<<<(NPH / 2 + 255) / 256, 256, 0, stream>>>(phase);
#endif

    for (int it = 0; it < NITER; ++it) {
        k_istft<<<NFRM, 256, 0, stream>>>(mag, phase, wins, tw, frames);
        k_ola<<<(NB * SIGL + 255) / 256, 256, 0, stream>>>(frames, sig);
        k_stft<<<NFRM, 256, 0, stream>>>(sig, winf, tw, phase);
    }
    k_istft<<<NFRM, 256, 0, stream>>>(mag, phase, wins, tw, frames);
    k_ola<<<(NB * SIGL + 255) / 256, 256, 0, stream>>>(frames, outp);
}

// Round 3
// 921.800 us; speedup vs baseline: 3.6311x; 1.3570x over previous
//
#include <hip/hip_runtime.h>
#include <math.h>

// ---------------- problem constants ----------------
#define NB     8
#define NT     1000
#define NMEL   80
#define NFREQ  513      // 1024/2+1
#define NFFT   1024
#define WINL   1024
#define HOP    256
#define SIGL   256768   // (NT-1)*HOP + WINL
#define NFRM   8000     // NB*NT
#define NPH    4104000  // NFRM*NFREQ
#define NITER  8

#define TFG_PARTITIONABLE 1

// padded LDS indexing for FFT buffers: +1 float2 per 64 (breaks pow2 bank strides)
#define IDX(x) ((x) + ((x) >> 6))
#define LDSN   (NFFT + (NFFT >> 6))   // 1040
#define TW3N   1023                    // packed per-stage twiddle triples

// ---------------- workspace layout (bytes) ----------------
#define OFF_G      ((size_t)0)                       // double G[80][80]
#define SZ_G       ((size_t)NMEL*NMEL*8)
#define OFF_GINV   (OFF_G + SZ_G)                    // double Ginv[80][80]
#define SZ_GINV    ((size_t)NMEL*NMEL*8)
#define OFF_INVMEL (OFF_GINV + SZ_GINV)              // float invmel[513][80]
#define SZ_INVMEL  ((size_t)NFREQ*NMEL*4)
#define OFF_WINF   (OFF_INVMEL + SZ_INVMEL)          // float winf[1024]
#define OFF_WINS   (OFF_WINF + 4096)                 // float wins[1024]
#define OFF_TW3    (OFF_WINS + 4096)                 // float2 tw3[1023]
#define OFF_MAG    (OFF_TW3 + 8192)                  // float mag[8000][513]
#define SZ_MAG     ((size_t)NFRM*NFREQ*4)
#define OFF_PH     (OFF_MAG + SZ_MAG)                // float2 phase[8000][513]
#define SZ_PH      ((size_t)NFRM*NFREQ*8)
#define OFF_MP     (OFF_PH + SZ_PH)                  // float melpow[8000][80]
#define SZ_MP      ((size_t)NFRM*NMEL*4)
#define OFF_FR     (OFF_MP + SZ_MP)                  // float frames[8000][1024]
#define SZ_FR      ((size_t)NFRM*NFFT*4)
#define OFF_SIG    (OFF_FR + SZ_FR)                  // float sig[8][256768]
#define SZ_SIG     ((size_t)NB*SIGL*4)

// ---------------- small precompute kernels ----------------

__global__ void k_windows(float* __restrict__ winf, float* __restrict__ wins,
                          float2* __restrict__ tw3) {
    int t = threadIdx.x; // 256 threads
    for (int n = t; n < WINL; n += 256) {
        double w = 0.5 - 0.5 * cos(2.0 * M_PI * (double)n / (double)WINL);
        winf[n] = (float)w;
    }
    __syncthreads();
    {
        float a0 = winf[t], a1 = winf[t + 256], a2 = winf[t + 512], a3 = winf[t + 768];
        float den = a0 * a0;
        den += a1 * a1; den += a2 * a2; den += a3 * a3;
        wins[t]       = a0 / den;
        wins[t + 256] = a1 / den;
        wins[t + 512] = a2 / den;
        wins[t + 768] = a3 / den;
    }
    // packed radix-4 twiddles: stage s, p<256>>2s: [W^p, W^2p, W^3p] of size-(1024>>2s) DFT
    const int BASE[5] = {0, 768, 960, 1008, 1020};
    for (int s = 0; s < 5; ++s) {
        int np = 256 >> (2 * s);
        for (int p = t; p < np; p += 256) {
            double ang = -2.0 * M_PI * (double)(p << (2 * s)) / 1024.0;
            for (int k = 1; k <= 3; ++k)
                tw3[BASE[s] + 3 * p + (k - 1)] =
                    make_float2((float)cos(k * ang), (float)sin(k * ang));
        }
    }
}

// G = B B^T (f64)
__global__ void k_gram(const float* __restrict__ Bm, double* __restrict__ G) {
    int i = blockIdx.x; // 80 blocks
    for (int j = threadIdx.x; j < NMEL; j += blockDim.x) {
        double s = 0.0;
        for (int f = 0; f < NFREQ; ++f)
            s += (double)Bm[i * NFREQ + f] * (double)Bm[j * NFREQ + f];
        G[i * NMEL + j] = s;
    }
}

// Register-tiled in-place Gauss-Jordan inversion of SPD 80x80.
// 16x16 thread grid, each thread owns a 5x5 f64 block in REGISTERS.
// Fully unrolled pivot loop -> all register indices compile-time.
__global__ __launch_bounds__(256) void k_gjinv(const double* __restrict__ G,
                                               double* __restrict__ Ginv) {
    __shared__ double fcol[2][NMEL];
    __shared__ double prow[2][NMEL];
    __shared__ double App[2];
    double A[5][5];
    const int t = threadIdx.x, tx = t & 15, ty = t >> 4;
    const int R0 = ty * 5, C0 = tx * 5;
#pragma unroll
    for (int r = 0; r < 5; ++r)
#pragma unroll
        for (int c = 0; c < 5; ++c)
            A[r][c] = G[(R0 + r) * NMEL + C0 + c];
    __syncthreads();
#pragma unroll
    for (int p = 0; p < NMEL; ++p) {
        const int pb = p / 5, pi = p % 5;   // compile-time (full unroll)
        const int cur = p & 1;
        // stage pivot column (pre-update values) + pivot element
        if (tx == pb) {
#pragma unroll
            for (int r = 0; r < 5; ++r) fcol[cur][R0 + r] = A[r][pi];
            if (ty == pb) App[cur] = A[pi][pi];
        }
        __syncthreads();
        const double d = 1.0 / App[cur];
        // scale pivot row, publish it
        if (ty == pb) {
#pragma unroll
            for (int c = 0; c < 5; ++c) {
                double v = (tx == pb && c == pi) ? d : A[pi][c] * d;
                A[pi][c] = v;
                prow[cur][C0 + c] = v;
            }
        }
        __syncthreads();
        double fr[5], pc[5];
#pragma unroll
        for (int r = 0; r < 5; ++r) fr[r] = fcol[cur][R0 + r];
#pragma unroll
        for (int c = 0; c < 5; ++c) pc[c] = prow[cur][C0 + c];
#pragma unroll
        for (int r = 0; r < 5; ++r) {
            const bool isPivRow = (ty == pb) && (r == pi);
            if (!isPivRow) {
#pragma unroll
                for (int c = 0; c < 5; ++c) {
                    const bool isPivCol = (tx == pb) && (c == pi);
                    A[r][c] = isPivCol ? (-fr[r] * d) : fma(-fr[r], pc[c], A[r][c]);
                }
            }
        }
        // no trailing barrier: next pivot stages into the other LDS buffer
    }
#pragma unroll
    for (int r = 0; r < 5; ++r)
#pragma unroll
        for (int c = 0; c < 5; ++c)
            Ginv[(R0 + r) * NMEL + C0 + c] = A[r][c];
}

// invmel[f][m] = sum_k B[k][f] * Ginv[k][m]
__global__ void k_invmel(const float* __restrict__ Bm, const double* __restrict__ Ginv,
                         float* __restrict__ invmel) {
    int idx = blockIdx.x * blockDim.x + threadIdx.x;
    if (idx >= NFREQ * NMEL) return;
    int f = idx / NMEL, m = idx - f * NMEL;
    double s = 0.0;
    for (int k = 0; k < NMEL; ++k)
        s += (double)Bm[k * NFREQ + f] * Ginv[k * NMEL + m];
    invmel[idx] = (float)s;
}

// melpow = 10^(mel*scale + mean)
__global__ void k_melpow(const float* __restrict__ mel, const float* __restrict__ smean,
                         const float* __restrict__ sscale, float* __restrict__ mp) {
    int idx = blockIdx.x * blockDim.x + threadIdx.x;
    if (idx >= NFRM * NMEL) return;
    int m = idx % NMEL;
    mp[idx] = exp10f(mel[idx] * sscale[m] + smean[m]);
}

// mag[bt][f] = max(1e-10, sum_m melpow[bt][m]*invmel[f][m])
__global__ __launch_bounds__(256) void k_mag(const float* __restrict__ mp,
                                             const float* __restrict__ invmel,
                                             float* __restrict__ mag) {
    __shared__ float row[NMEL];
    int bt = blockIdx.x;
    for (int m = threadIdx.x; m < NMEL; m += 256) row[m] = mp[(size_t)bt * NMEL + m];
    __syncthreads();
    for (int f = threadIdx.x; f < NFREQ; f += 256) {
        float s = 0.f;
        const float* iv = invmel + (size_t)f * NMEL;
        for (int m = 0; m < NMEL; ++m) s += row[m] * iv[m];
        mag[(size_t)bt * NFREQ + f] = fmaxf(1e-10f, s);
    }
}

// ---------------- threefry2x32 (JAX-exact) ----------------
__device__ inline unsigned rotl32(unsigned x, int d) { return (x << d) | (x >> (32 - d)); }

__device__ inline void threefry2x32(unsigned k0, unsigned k1, unsigned& x0, unsigned& x1) {
    unsigned ks0 = k0, ks1 = k1, ks2 = k0 ^ k1 ^ 0x1BD11BDAu;
    x0 += ks0; x1 += ks1;
#define TFR(r) { x0 += x1; x1 = rotl32(x1, r); x1 ^= x0; }
    TFR(13) TFR(15) TFR(26) TFR(6)   x0 += ks1; x1 += ks2 + 1u;
    TFR(17) TFR(29) TFR(16) TFR(24)  x0 += ks2; x1 += ks0 + 2u;
    TFR(13) TFR(15) TFR(26) TFR(6)   x0 += ks0; x1 += ks1 + 3u;
    TFR(17) TFR(29) TFR(16) TFR(24)  x0 += ks1; x1 += ks2 + 4u;
    TFR(13) TFR(15) TFR(26) TFR(6)   x0 += ks2; x1 += ks0 + 5u;
#undef TFR
}

__device__ inline float bits_to_unit(unsigned bits) {
    return __uint_as_float((bits >> 9) | 0x3F800000u) - 1.0f;
}

__device__ inline float2 unit_to_phase(float u) {
    float ang = 6.283185307179586f * u;
    return make_float2(cosf(ang), sinf(ang));
}

__global__ void k_phase_init(float2* __restrict__ phase) {
#if TFG_PARTITIONABLE
    int i = blockIdx.x * blockDim.x + threadIdx.x;
    if (i >= NPH) return;
    unsigned x0 = 0u, x1 = (unsigned)i;
    threefry2x32(0u, 1u, x0, x1);
    unsigned bits = x0 ^ x1;
    phase[i] = unit_to_phase(bits_to_unit(bits));
#else
    const int half = NPH / 2;
    int i = blockIdx.x * blockDim.x + threadIdx.x;
    if (i >= half) return;
    unsigned x0 = (unsigned)i, x1 = (unsigned)(i + half);
    threefry2x32(0u, 1u, x0, x1);
    phase[i]        = unit_to_phase(bits_to_unit(x0));
    phase[i + half] = unit_to_phase(bits_to_unit(x1));
#endif
}

// ---------------- 1024-pt radix-4 Stockham FFT in LDS ----------------
// 5 stages; reads always at {w, w+256, w+512, w+768}; result in returned buffer.
template <bool INV>
__device__ inline float2* fft1024_r4(float2* a, float2* b, const float2* __restrict__ t3) {
    constexpr int BASE[5] = {0, 768, 960, 1008, 1020};
    const int w = threadIdx.x;
#pragma unroll
    for (int s = 0; s < 5; ++s) {
        const int slog = 2 * s;
        const int q = w & ((1 << slog) - 1);
        const int p = w >> slog;
        float2 x0 = a[IDX(w)];
        float2 x1 = a[IDX(w + 256)];
        float2 x2 = a[IDX(w + 512)];
        float2 x3 = a[IDX(w + 768)];
        float2 t0 = make_float2(x0.x + x2.x, x0.y + x2.y);
        float2 t1 = make_float2(x0.x - x2.x, x0.y - x2.y);
        float2 t2 = make_float2(x1.x + x3.x, x1.y + x3.y);
        float2 tm = make_float2(x1.x - x3.x, x1.y - x3.y);
        // forward: -i*tm ; inverse: +i*tm
        float2 it3 = INV ? make_float2(-tm.y, tm.x) : make_float2(tm.y, -tm.x);
        float2 y0 = make_float2(t0.x + t2.x, t0.y + t2.y);
        float2 u1 = make_float2(t1.x + it3.x, t1.y + it3.y);
        float2 u2 = make_float2(t0.x - t2.x, t0.y - t2.y);
        float2 u3 = make_float2(t1.x - it3.x, t1.y - it3.y);
        const float2* tp = t3 + BASE[s] + 3 * p;
        float2 w1 = tp[0], w2 = tp[1], w3 = tp[2];
        float s1 = INV ? -w1.y : w1.y;
        float s2 = INV ? -w2.y : w2.y;
        float s3 = INV ? -w3.y : w3.y;
        float2 y1 = make_float2(u1.x * w1.x - u1.y * s1, u1.x * s1 + u1.y * w1.x);
        float2 y2 = make_float2(u2.x * w2.x - u2.y * s2, u2.x * s2 + u2.y * w2.x);
        float2 y3 = make_float2(u3.x * w3.x - u3.y * s3, u3.x * s3 + u3.y * w3.x);
        const int wb = q + (p << (slog + 2));
        b[IDX(wb)]                = y0;
        b[IDX(wb + (1 << slog))]  = y1;
        b[IDX(wb + (2 << slog))]  = y2;
        b[IDX(wb + (3 << slog))]  = y3;
        __syncthreads();
        float2* tsw = a; a = b; b = tsw;
    }
    return a;
}

// ISTFT frame: spec = mag*phase -> Hermitian extend -> ifft -> *syn_win -> frames
__global__ __launch_bounds__(256) void k_istft(const float* __restrict__ mag,
                                               const float2* __restrict__ phase,
                                               const float* __restrict__ wins,
                                               const float2* __restrict__ tw3g,
                                               float* __restrict__ frames) {
    __shared__ float2 bufA[LDSN];
    __shared__ float2 bufB[LDSN];
    __shared__ float2 t3[TW3N];
    int bt = blockIdx.x;
    const float*  mg = mag   + (size_t)bt * NFREQ;
    const float2* ph = phase + (size_t)bt * NFREQ;
    int t = threadIdx.x;
    for (int k = t; k < TW3N; k += 256) t3[k] = tw3g[k];
    for (int k = t; k < NFFT; k += 256) {
        float2 sv;
        if (k <= 512) {
            float m = mg[k]; float2 p = ph[k];
            sv = make_float2(m * p.x, m * p.y);
        } else {
            int kk = NFFT - k;
            float m = mg[kk]; float2 p = ph[kk];
            sv = make_float2(m * p.x, -m * p.y);
        }
        bufA[IDX(k)] = sv;
    }
    __syncthreads();
    float2* res = fft1024_r4<true>(bufA, bufB, t3);
    float* out = frames + (size_t)bt * NFFT;
    const float inv = 1.0f / (float)NFFT;
    for (int n = t; n < NFFT; n += 256)
        out[n] = res[IDX(n)].x * inv * wins[n];
}

// overlap-add (gather): sig[b][l] = sum_t frames[b*NT+t][l-256t]
__global__ void k_ola(const float* __restrict__ frames, float* __restrict__ sig) {
    int idx = blockIdx.x * blockDim.x + threadIdx.x;
    if (idx >= NB * SIGL) return;
    int b = idx / SIGL, l = idx - b * SIGL;
    int tmax = min(NT - 1, l >> 8);
    int tmin = (l >= WINL) ? ((l - (WINL - HOP)) >> 8) : 0;
    float s = 0.f;
    for (int t = tmin; t <= tmax; ++t)
        s += frames[((size_t)(b * NT + t)) * NFFT + (l - (t << 8))];
    sig[idx] = s;
}

// STFT frame + phase normalize
__global__ __launch_bounds__(256) void k_stft(const float* __restrict__ sig,
                                              const float* __restrict__ winf,
                                              const float2* __restrict__ tw3g,
                                              float2* __restrict__ phase) {
    __shared__ float2 bufA[LDSN];
    __shared__ float2 bufB[LDSN];
    __shared__ float2 t3[TW3N];
    int bt = blockIdx.x;
    int b = bt / NT, tt = bt - b * NT;
    const float* x = sig + (size_t)b * SIGL + (size_t)tt * HOP;
    int t = threadIdx.x;
    for (int k = t; k < TW3N; k += 256) t3[k] = tw3g[k];
    for (int n = t; n < NFFT; n += 256)
        bufA[IDX(n)] = make_float2(x[n] * winf[n], 0.f);
    __syncthreads();
    float2* res = fft1024_r4<false>(bufA, bufB, t3);
    for (int f = t; f <= 512; f += 256) {
        float2 p = res[IDX(f)];
        float a = sqrtf(p.x * p.x + p.y * p.y);
        float inv = 1.0f / fmaxf(1e-10f, a);
        phase[(size_t)bt * NFREQ + f] = make_float2(p.x * inv, p.y * inv);
    }
}

// ---------------- launcher ----------------
extern "C" void kernel_launch(void* const* d_in, const int* in_sizes, int n_in,
                              void* d_out, int out_size, void* d_ws, size_t ws_size,
                              hipStream_t stream) {
    const float* mel    = (const float*)d_in[0];
    const float* basis  = (const float*)d_in[1];
    const float* smean  = (const float*)d_in[2];
    const float* sscale = (const float*)d_in[3];

    char* ws = (char*)d_ws;
    double* G      = (double*)(ws + OFF_G);
    double* Ginv   = (double*)(ws + OFF_GINV);
    float*  invmel = (float*) (ws + OFF_INVMEL);
    float*  winf   = (float*) (ws + OFF_WINF);
    float*  wins   = (float*) (ws + OFF_WINS);
    float2* tw3    = (float2*)(ws + OFF_TW3);
    float*  mag    = (float*) (ws + OFF_MAG);
    float2* phase  = (float2*)(ws + OFF_PH);
    float*  mp     = (float*) (ws + OFF_MP);
    float*  frames = (float*) (ws + OFF_FR);
    float*  sig    = (float*) (ws + OFF_SIG);
    float*  outp   = (float*)d_out;

    k_windows<<<1, 256, 0, stream>>>(winf, wins, tw3);
    k_gram<<<80, 256, 0, stream>>>(basis, G);
    k_gjinv<<<1, 256, 0, stream>>>(G, Ginv);
    k_invmel<<<(NFREQ * NMEL + 255) / 256, 256, 0, stream>>>(basis, Ginv, invmel);
    k_melpow<<<(NFRM * NMEL + 255) / 256, 256, 0, stream>>>(mel, smean, sscale, mp);
    k_mag<<<NFRM, 256, 0, stream>>>(mp, invmel, mag);
#if TFG_PARTITIONABLE
    k_phase_init<<<(NPH + 255) / 256, 256, 0, stream>>>(phase);
#else
    k_phase_init<<<(NPH / 2 + 255) / 256, 256, 0, stream>>>(phase);
#endif

    for (int it = 0; it < NITER; ++it) {
        k_istft<<<NFRM, 256, 0, stream>>>(mag, phase, wins, tw3, frames);
        k_ola<<<(NB * SIGL + 255) / 256, 256, 0, stream>>>(frames, sig);
        k_stft<<<NFRM, 256, 0, stream>>>(sig, winf, tw3, phase);
    }
    k_istft<<<NFRM, 256, 0, stream>>>(mag, phase, wins, tw3, frames);
    k_ola<<<(NB * SIGL + 255) / 256, 256, 0, stream>>>(frames, outp);
}

// Round 4
// 620.429 us; speedup vs baseline: 5.3949x; 1.4857x over previous
//
#include <hip/hip_runtime.h>
#include <math.h>

// ---------------- problem constants ----------------
#define NB     8
#define NT     1000
#define NMEL   80
#define NFREQ  513      // 1024/2+1
#define NFFT   1024
#define WINL   1024
#define HOP    256
#define SIGL   256768   // (NT-1)*HOP + WINL
#define NFRM   8000     // NB*NT
#define NPH    4104000  // NFRM*NFREQ
#define NITER  8

#define TFG_PARTITIONABLE 1

// padded LDS indexing for FFT buffers
#define IDX(x) ((x) + ((x) >> 6))
#define LDS512 520      // IDX(511)=518 max
#define TW3N   510      // packed radix-4 triples for 512-pt (128+32+8+2)*3
#define PPN    513      // W_1024^k, k=0..512

// ---------------- workspace layout (bytes) ----------------
#define OFF_G      ((size_t)0)                       // double G[80][80]
#define SZ_G       ((size_t)NMEL*NMEL*8)
#define OFF_GINV   (OFF_G + SZ_G)
#define SZ_GINV    ((size_t)NMEL*NMEL*8)
#define OFF_INVMEL (OFF_GINV + SZ_GINV)              // float invmelT[80][513]
#define SZ_INVMEL  ((size_t)NFREQ*NMEL*4)
#define OFF_WINF   (OFF_INVMEL + SZ_INVMEL)          // float winf[1024]
#define OFF_WINS   (OFF_WINF + 4096)                 // float wins[1024]
#define OFF_TW3    (OFF_WINS + 4096)                 // float2 tw3[510]
#define OFF_PP     (OFF_TW3 + 4096)                  // float2 pp[513]
#define OFF_MAG    (OFF_PP + 8192)                   // float mag[8000][513]
#define SZ_MAG     ((size_t)NFRM*NFREQ*4)
#define OFF_PH     (OFF_MAG + SZ_MAG)                // float2 phase[8000][513]
#define SZ_PH      ((size_t)NFRM*NFREQ*8)
#define OFF_MP     (OFF_PH + SZ_PH)                  // float melpow[8000][80]
#define SZ_MP      ((size_t)NFRM*NMEL*4)
#define OFF_FR     (OFF_MP + SZ_MP)                  // float frames[8000][1024]
#define SZ_FR      ((size_t)NFRM*NFFT*4)
#define OFF_SIG    (OFF_FR + SZ_FR)                  // float sig[8][256768]
#define SZ_SIG     ((size_t)NB*SIGL*4)

// ---------------- small precompute kernels ----------------

__global__ void k_windows(float* __restrict__ winf, float* __restrict__ wins,
                          float2* __restrict__ tw3, float2* __restrict__ pp) {
    int t = threadIdx.x; // 256 threads
    for (int n = t; n < WINL; n += 256) {
        double w = 0.5 - 0.5 * cos(2.0 * M_PI * (double)n / (double)WINL);
        winf[n] = (float)w;
    }
    __syncthreads();
    {
        float a0 = winf[t], a1 = winf[t + 256], a2 = winf[t + 512], a3 = winf[t + 768];
        float den = a0 * a0;
        den += a1 * a1; den += a2 * a2; den += a3 * a3;
        wins[t]       = a0 / den;
        wins[t + 256] = a1 / den;
        wins[t + 512] = a2 / den;
        wins[t + 768] = a3 / den;
    }
    // packed radix-4 twiddles for 512-pt: stage s, p < 128>>2s: [W^p, W^2p, W^3p]
    const int BASE[4] = {0, 384, 480, 504};
    for (int s = 0; s < 4; ++s) {
        int np = 128 >> (2 * s);
        for (int p = t; p < np; p += 256) {
            double ang = -2.0 * M_PI * (double)(p << (2 * s)) / 512.0;
            for (int k = 1; k <= 3; ++k)
                tw3[BASE[s] + 3 * p + (k - 1)] =
                    make_float2((float)cos(k * ang), (float)sin(k * ang));
        }
    }
    // pp[k] = e^{-2*pi*i*k/1024}
    for (int k = t; k < PPN; k += 256) {
        double ang = -2.0 * M_PI * (double)k / 1024.0;
        pp[k] = make_float2((float)cos(ang), (float)sin(ang));
    }
}

// G = B B^T (f64)
__global__ void k_gram(const float* __restrict__ Bm, double* __restrict__ G) {
    int i = blockIdx.x; // 80 blocks
    for (int j = threadIdx.x; j < NMEL; j += blockDim.x) {
        double s = 0.0;
        for (int f = 0; f < NFREQ; ++f)
            s += (double)Bm[i * NFREQ + f] * (double)Bm[j * NFREQ + f];
        G[i * NMEL + j] = s;
    }
}

// Register-tiled in-place Gauss-Jordan inversion of SPD 80x80 (proven round 3).
__global__ __launch_bounds__(256) void k_gjinv(const double* __restrict__ G,
                                               double* __restrict__ Ginv) {
    __shared__ double fcol[2][NMEL];
    __shared__ double prow[2][NMEL];
    __shared__ double App[2];
    double A[5][5];
    const int t = threadIdx.x, tx = t & 15, ty = t >> 4;
    const int R0 = ty * 5, C0 = tx * 5;
#pragma unroll
    for (int r = 0; r < 5; ++r)
#pragma unroll
        for (int c = 0; c < 5; ++c)
            A[r][c] = G[(R0 + r) * NMEL + C0 + c];
    __syncthreads();
#pragma unroll
    for (int p = 0; p < NMEL; ++p) {
        const int pb = p / 5, pi = p % 5;
        const int cur = p & 1;
        if (tx == pb) {
#pragma unroll
            for (int r = 0; r < 5; ++r) fcol[cur][R0 + r] = A[r][pi];
            if (ty == pb) App[cur] = A[pi][pi];
        }
        __syncthreads();
        const double d = 1.0 / App[cur];
        if (ty == pb) {
#pragma unroll
            for (int c = 0; c < 5; ++c) {
                double v = (tx == pb && c == pi) ? d : A[pi][c] * d;
                A[pi][c] = v;
                prow[cur][C0 + c] = v;
            }
        }
        __syncthreads();
        double fr[5], pc[5];
#pragma unroll
        for (int r = 0; r < 5; ++r) fr[r] = fcol[cur][R0 + r];
#pragma unroll
        for (int c = 0; c < 5; ++c) pc[c] = prow[cur][C0 + c];
#pragma unroll
        for (int r = 0; r < 5; ++r) {
            const bool isPivRow = (ty == pb) && (r == pi);
            if (!isPivRow) {
#pragma unroll
                for (int c = 0; c < 5; ++c) {
                    const bool isPivCol = (tx == pb) && (c == pi);
                    A[r][c] = isPivCol ? (-fr[r] * d) : fma(-fr[r], pc[c], A[r][c]);
                }
            }
        }
    }
#pragma unroll
    for (int r = 0; r < 5; ++r)
#pragma unroll
        for (int c = 0; c < 5; ++c)
            Ginv[(R0 + r) * NMEL + C0 + c] = A[r][c];
}

// invmelT[m][f] = sum_k B[k][f] * Ginv[k][m]   (TRANSPOSED output)
__global__ void k_invmel(const float* __restrict__ Bm, const double* __restrict__ Ginv,
                         float* __restrict__ ivT) {
    int idx = blockIdx.x * blockDim.x + threadIdx.x;
    if (idx >= NFREQ * NMEL) return;
    int f = idx / NMEL, m = idx - f * NMEL;
    double s = 0.0;
    for (int k = 0; k < NMEL; ++k)
        s += (double)Bm[k * NFREQ + f] * Ginv[k * NMEL + m];
    ivT[m * NFREQ + f] = (float)s;
}

// melpow = 10^(mel*scale + mean)
__global__ void k_melpow(const float* __restrict__ mel, const float* __restrict__ smean,
                         const float* __restrict__ sscale, float* __restrict__ mp) {
    int idx = blockIdx.x * blockDim.x + threadIdx.x;
    if (idx >= NFRM * NMEL) return;
    int m = idx % NMEL;
    mp[idx] = exp10f(mel[idx] * sscale[m] + smean[m]);
}

// mag: 8 bt-rows per block, coalesced ivT reads, LDS-broadcast mp rows
#define MAGROWS 8
__global__ __launch_bounds__(256) void k_mag(const float* __restrict__ mp,
                                             const float* __restrict__ ivT,
                                             float* __restrict__ mag) {
    __shared__ float rows[MAGROWS][NMEL];
    int bt0 = blockIdx.x * MAGROWS;
    for (int e = threadIdx.x; e < MAGROWS * NMEL; e += 256)
        rows[e / NMEL][e % NMEL] = mp[(size_t)bt0 * NMEL + e];
    __syncthreads();
    for (int f = threadIdx.x; f < NFREQ; f += 256) {
        float acc[MAGROWS];
#pragma unroll
        for (int r = 0; r < MAGROWS; ++r) acc[r] = 0.f;
        for (int m = 0; m < NMEL; ++m) {
            float iv = ivT[m * NFREQ + f];
#pragma unroll
            for (int r = 0; r < MAGROWS; ++r) acc[r] = fmaf(rows[r][m], iv, acc[r]);
        }
#pragma unroll
        for (int r = 0; r < MAGROWS; ++r)
            mag[(size_t)(bt0 + r) * NFREQ + f] = fmaxf(1e-10f, acc[r]);
    }
}

// ---------------- threefry2x32 (JAX-exact) ----------------
__device__ inline unsigned rotl32(unsigned x, int d) { return (x << d) | (x >> (32 - d)); }

__device__ inline void threefry2x32(unsigned k0, unsigned k1, unsigned& x0, unsigned& x1) {
    unsigned ks0 = k0, ks1 = k1, ks2 = k0 ^ k1 ^ 0x1BD11BDAu;
    x0 += ks0; x1 += ks1;
#define TFR(r) { x0 += x1; x1 = rotl32(x1, r); x1 ^= x0; }
    TFR(13) TFR(15) TFR(26) TFR(6)   x0 += ks1; x1 += ks2 + 1u;
    TFR(17) TFR(29) TFR(16) TFR(24)  x0 += ks2; x1 += ks0 + 2u;
    TFR(13) TFR(15) TFR(26) TFR(6)   x0 += ks0; x1 += ks1 + 3u;
    TFR(17) TFR(29) TFR(16) TFR(24)  x0 += ks1; x1 += ks2 + 4u;
    TFR(13) TFR(15) TFR(26) TFR(6)   x0 += ks2; x1 += ks0 + 5u;
#undef TFR
}

__device__ inline float bits_to_unit(unsigned bits) {
    return __uint_as_float((bits >> 9) | 0x3F800000u) - 1.0f;
}

__device__ inline float2 unit_to_phase(float u) {
    float ang = 6.283185307179586f * u;
    return make_float2(cosf(ang), sinf(ang));
}

__global__ void k_phase_init(float2* __restrict__ phase) {
#if TFG_PARTITIONABLE
    int i = blockIdx.x * blockDim.x + threadIdx.x;
    if (i >= NPH) return;
    unsigned x0 = 0u, x1 = (unsigned)i;
    threefry2x32(0u, 1u, x0, x1);
    unsigned bits = x0 ^ x1;
    phase[i] = unit_to_phase(bits_to_unit(bits));
#else
    const int half = NPH / 2;
    int i = blockIdx.x * blockDim.x + threadIdx.x;
    if (i >= half) return;
    unsigned x0 = (unsigned)i, x1 = (unsigned)(i + half);
    threefry2x32(0u, 1u, x0, x1);
    phase[i]        = unit_to_phase(bits_to_unit(x0));
    phase[i + half] = unit_to_phase(bits_to_unit(x1));
#endif
}

// ---------------- 512-pt complex FFT (radix-4 x4 + radix-2), 128 lanes/frame ----
template <bool INV>
__device__ inline float2* fft512(float2* a, float2* b, const float2* __restrict__ t3,
                                 const int w) {
    constexpr int BASE[4] = {0, 384, 480, 504};
#pragma unroll
    for (int s = 0; s < 4; ++s) {
        const int slog = 2 * s;
        const int q = w & ((1 << slog) - 1);
        const int p = w >> slog;
        float2 x0 = a[IDX(w)];
        float2 x1 = a[IDX(w + 128)];
        float2 x2 = a[IDX(w + 256)];
        float2 x3 = a[IDX(w + 384)];
        float2 t0 = make_float2(x0.x + x2.x, x0.y + x2.y);
        float2 t1 = make_float2(x0.x - x2.x, x0.y - x2.y);
        float2 t2 = make_float2(x1.x + x3.x, x1.y + x3.y);
        float2 tm = make_float2(x1.x - x3.x, x1.y - x3.y);
        float2 it3 = INV ? make_float2(-tm.y, tm.x) : make_float2(tm.y, -tm.x);
        float2 y0 = make_float2(t0.x + t2.x, t0.y + t2.y);
        float2 u1 = make_float2(t1.x + it3.x, t1.y + it3.y);
        float2 u2 = make_float2(t0.x - t2.x, t0.y - t2.y);
        float2 u3 = make_float2(t1.x - it3.x, t1.y - it3.y);
        const float2* tp = t3 + BASE[s] + 3 * p;
        float2 w1 = tp[0], w2 = tp[1], w3 = tp[2];
        float s1 = INV ? -w1.y : w1.y;
        float s2 = INV ? -w2.y : w2.y;
        float s3 = INV ? -w3.y : w3.y;
        float2 y1 = make_float2(u1.x * w1.x - u1.y * s1, u1.x * s1 + u1.y * w1.x);
        float2 y2 = make_float2(u2.x * w2.x - u2.y * s2, u2.x * s2 + u2.y * w2.x);
        float2 y3 = make_float2(u3.x * w3.x - u3.y * s3, u3.x * s3 + u3.y * w3.x);
        const int wb = q + (p << (slog + 2));
        b[IDX(wb)]               = y0;
        b[IDX(wb + (1 << slog))] = y1;
        b[IDX(wb + (2 << slog))] = y2;
        b[IDX(wb + (3 << slog))] = y3;
        __syncthreads();
        float2* tsw = a; a = b; b = tsw;
    }
    // final radix-2 (twiddle-free), 2 butterflies/lane
#pragma unroll
    for (int r = 0; r < 2; ++r) {
        const int bb = w + 128 * r;
        float2 x0 = a[IDX(bb)];
        float2 x1 = a[IDX(bb + 256)];
        b[IDX(bb)]       = make_float2(x0.x + x1.x, x0.y + x1.y);
        b[IDX(bb + 256)] = make_float2(x0.x - x1.x, x0.y - x1.y);
    }
    __syncthreads();
    return b;
}

// ISTFT: X=mag*phase -> pack Z=Xe+i*Xo -> IFFT512 -> x[2n]=Re, x[2n+1]=Im -> *syn
// Two frames per block (lanes 0-127 / 128-255).
__global__ __launch_bounds__(256) void k_istft(const float* __restrict__ mag,
                                               const float2* __restrict__ phase,
                                               const float* __restrict__ wins,
                                               const float2* __restrict__ tw3g,
                                               const float2* __restrict__ ppg,
                                               float* __restrict__ frames) {
    __shared__ float2 XS[2][513];
    __shared__ float2 A[2][LDS512];
    __shared__ float2 B[2][LDS512];
    __shared__ float2 t3[TW3N];
    __shared__ float2 pp[PPN];
    const int t = threadIdx.x, sub = t >> 7, w = t & 127;
    const int bt = blockIdx.x * 2 + sub;
    for (int k = t; k < TW3N; k += 256) t3[k] = tw3g[k];
    for (int k = t; k < PPN; k += 256) pp[k] = ppg[k];
    const float*  mg = mag   + (size_t)bt * NFREQ;
    const float2* ph = phase + (size_t)bt * NFREQ;
#pragma unroll
    for (int j = 0; j < 5; ++j) {
        int k = w + 128 * j;
        if (k <= 512) {
            float m = mg[k]; float2 p = ph[k];
            float2 X = make_float2(m * p.x, m * p.y);
            if (k == 0 || k == 512) X.y = 0.f;   // C2R drops imag of DC/Nyquist
            XS[sub][k] = X;
        }
    }
    __syncthreads();
#pragma unroll
    for (int j = 0; j < 4; ++j) {
        int k = w + 128 * j;
        float2 Xk = XS[sub][k];
        float2 Xc = XS[sub][512 - k];
        float ex = 0.5f * (Xk.x + Xc.x), ey = 0.5f * (Xk.y - Xc.y);
        float dx = 0.5f * (Xk.x - Xc.x), dy = 0.5f * (Xk.y + Xc.y);
        float2 c = pp[k];                         // e^{-i th}; W^{-k} = conj(c)
        float ox = c.x * dx + c.y * dy;
        float oy = c.x * dy - c.y * dx;
        A[sub][IDX(k)] = make_float2(ex - oy, ey + ox);   // Z = Xe + i Xo
    }
    __syncthreads();
    float2* res = fft512<true>(&A[sub][0], &B[sub][0], t3, w);
    float2* out2 = (float2*)(frames + (size_t)bt * NFFT);
    const float2* wn2 = (const float2*)wins;
    const float inv = 1.0f / 512.0f;
#pragma unroll
    for (int j = 0; j < 4; ++j) {
        int n = w + 128 * j;
        float2 z = res[IDX(n)];
        float2 wv = wn2[n];
        out2[n] = make_float2(z.x * inv * wv.x, z.y * inv * wv.y);
    }
}

// overlap-add (gather): sig[b][l] = sum_t frames[b*NT+t][l-256t]
__global__ void k_ola(const float* __restrict__ frames, float* __restrict__ sig) {
    int idx = blockIdx.x * blockDim.x + threadIdx.x;
    if (idx >= NB * SIGL) return;
    int b = idx / SIGL, l = idx - b * SIGL;
    int tmax = min(NT - 1, l >> 8);
    int tmin = (l >= WINL) ? ((l - (WINL - HOP)) >> 8) : 0;
    float s = 0.f;
    for (int t = tmin; t <= tmax; ++t)
        s += frames[((size_t)(b * NT + t)) * NFFT + (l - (t << 8))];
    sig[idx] = s;
}

// STFT: z[n]=x[2n]w+i x[2n+1]w -> FFT512 -> unpack X[k] -> phase normalize
__global__ __launch_bounds__(256) void k_stft(const float* __restrict__ sig,
                                              const float* __restrict__ winf,
                                              const float2* __restrict__ tw3g,
                                              const float2* __restrict__ ppg,
                                              float2* __restrict__ phase) {
    __shared__ float2 A[2][LDS512];
    __shared__ float2 B[2][LDS512];
    __shared__ float2 t3[TW3N];
    __shared__ float2 pp[PPN];
    const int t = threadIdx.x, sub = t >> 7, w = t & 127;
    const int bt = blockIdx.x * 2 + sub;
    const int b = bt / NT, tt = bt - b * NT;
    const float2* x2 = (const float2*)(sig + (size_t)b * SIGL + (size_t)tt * HOP);
    const float2* wf2 = (const float2*)winf;
    for (int k = t; k < TW3N; k += 256) t3[k] = tw3g[k];
    for (int k = t; k < PPN; k += 256) pp[k] = ppg[k];
#pragma unroll
    for (int j = 0; j < 4; ++j) {
        int n = w + 128 * j;
        float2 v = x2[n];
        float2 wv = wf2[n];
        A[sub][IDX(n)] = make_float2(v.x * wv.x, v.y * wv.y);
    }
    __syncthreads();
    float2* res = fft512<false>(&A[sub][0], &B[sub][0], t3, w);
    float2* out = phase + (size_t)bt * NFREQ;
#pragma unroll
    for (int j = 0; j < 5; ++j) {
        int k = w + 128 * j;
        if (k > 512) break;
        float2 X;
        if (k == 0 || k == 512) {
            float2 z0 = res[IDX(0)];
            X = make_float2((k == 0) ? (z0.x + z0.y) : (z0.x - z0.y), 0.f);
        } else {
            float2 Zk = res[IDX(k)];
            float2 Zc = res[IDX(512 - k)];
            float ex = 0.5f * (Zk.x + Zc.x), ey = 0.5f * (Zk.y - Zc.y);
            float dx = 0.5f * (Zk.x - Zc.x), dy = 0.5f * (Zk.y + Zc.y);
            float ox = dy, oy = -dx;              // O = -i*d
            float2 c = pp[k];                      // W^{+k} in e^{-i} convention
            X = make_float2(ex + c.x * ox - c.y * oy, ey + c.x * oy + c.y * ox);
        }
        float aab = sqrtf(X.x * X.x + X.y * X.y);
        float iv = 1.0f / fmaxf(1e-10f, aab);
        out[k] = make_float2(X.x * iv, X.y * iv);
    }
}

// ---------------- launcher ----------------
extern "C" void kernel_launch(void* const* d_in, const int* in_sizes, int n_in,
                              void* d_out, int out_size, void* d_ws, size_t ws_size,
                              hipStream_t stream) {
    const float* mel    = (const float*)d_in[0];
    const float* basis  = (const float*)d_in[1];
    const float* smean  = (const float*)d_in[2];
    const float* sscale = (const float*)d_in[3];

    char* ws = (char*)d_ws;
    double* G      = (double*)(ws + OFF_G);
    double* Ginv   = (double*)(ws + OFF_GINV);
    float*  ivT    = (float*) (ws + OFF_INVMEL);
    float*  winf   = (float*) (ws + OFF_WINF);
    float*  wins   = (float*) (ws + OFF_WINS);
    float2* tw3    = (float2*)(ws + OFF_TW3);
    float2* pp     = (float2*)(ws + OFF_PP);
    float*  mag    = (float*) (ws + OFF_MAG);
    float2* phase  = (float2*)(ws + OFF_PH);
    float*  mp     = (float*) (ws + OFF_MP);
    float*  frames = (float*) (ws + OFF_FR);
    float*  sig    = (float*) (ws + OFF_SIG);
    float*  outp   = (float*)d_out;

    k_windows<<<1, 256, 0, stream>>>(winf, wins, tw3, pp);
    k_gram<<<80, 256, 0, stream>>>(basis, G);
    k_gjinv<<<1, 256, 0, stream>>>(G, Ginv);
    k_invmel<<<(NFREQ * NMEL + 255) / 256, 256, 0, stream>>>(basis, Ginv, ivT);
    k_melpow<<<(NFRM * NMEL + 255) / 256, 256, 0, stream>>>(mel, smean, sscale, mp);
    k_mag<<<NFRM / MAGROWS, 256, 0, stream>>>(mp, ivT, mag);
#if TFG_PARTITIONABLE
    k_phase_init<<<(NPH + 255) / 256, 256, 0, stream>>>(phase);
#else
    k_phase_init<<<(NPH / 2 + 255) / 256, 256, 0, stream>>>(phase);
#endif

    for (int it = 0; it < NITER; ++it) {
        k_istft<<<NFRM / 2, 256, 0, stream>>>(mag, phase, wins, tw3, pp, frames);
        k_ola<<<(NB * SIGL + 255) / 256, 256, 0, stream>>>(frames, sig);
        k_stft<<<NFRM / 2, 256, 0, stream>>>(sig, winf, tw3, pp, phase);
    }
    k_istft<<<NFRM / 2, 256, 0, stream>>>(mag, phase, wins, tw3, pp, frames);
    k_ola<<<(NB * SIGL + 255) / 256, 256, 0, stream>>>(frames, outp);
}